// Round 1
// baseline (1245.329 us; speedup 1.0000x reference)
//
#include <hip/hip_runtime.h>

// LSTM T=2048,B=2048,H=32,I=1,O=1 fully fused in ONE kernel.
// Decomposition: 32 threads per batch element (one per hidden unit j).
// Each thread holds W_hh rows {j, j+32, j+64, j+96} (128 VGPRs), h/c state,
// and broadcasts h through LDS wave-synchronously (groups of 32 lanes live
// inside one wave64 -> no s_barrier ever; DS pipe is in-order per wave).
// Grid: 256 blocks x 256 threads = 65536 threads = 1024 waves = 1 wave/SIMD.

namespace {
constexpr int T_ = 2048;
constexpr int B_ = 2048;
constexpr int H_ = 32;
constexpr int GPB = 8;              // batch groups (32 threads) per block
constexpr int OUTS = T_ * B_;       // 4194304 floats of outs [T,B,1]
constexpr int CHUNK = 32;           // timesteps of x staged per LDS chunk
constexpr int NCH = T_ / CHUNK;     // 64

__device__ __forceinline__ float sigmoidf_fast(float v) {
    // sigmoid(v) = 1 / (1 + 2^(-v*log2(e))) ; saturates correctly at +-inf
    return __builtin_amdgcn_rcpf(1.0f + __builtin_amdgcn_exp2f(-1.442695040888963f * v));
}
__device__ __forceinline__ float tanhf_fast(float v) {
    // tanh(v) = 1 - 2/(2^(2v*log2(e)) + 1) ; saturates correctly at +-inf
    return 1.0f - 2.0f * __builtin_amdgcn_rcpf(1.0f + __builtin_amdgcn_exp2f(2.885390081777927f * v));
}
} // namespace

__global__ __launch_bounds__(256, 1) void lstm_fused(
    const float* __restrict__ x,      // [T,B,1]
    const float* __restrict__ W_ih,   // [4H,1]
    const float* __restrict__ W_hh,   // [4H,H]
    const float* __restrict__ b_ih,   // [4H]
    const float* __restrict__ b_hh,   // [4H]
    const float* __restrict__ W_out,  // [1,H]
    const float* __restrict__ b_out,  // [1]
    float* __restrict__ out)          // outs | hT | cT
{
    const int j   = threadIdx.x & 31;   // hidden unit
    const int grp = threadIdx.x >> 5;   // batch group within block
    const int b   = blockIdx.x * GPB + grp;

    __shared__ float hbuf[GPB][H_];     // h broadcast buffer per group
    __shared__ float xbuf[GPB][CHUNK];  // staged x chunk per group

    // Per-thread recurrent weight rows for gates i,f,g,o of unit j.
    float w0[H_], w1[H_], w2[H_], w3[H_];
#pragma unroll
    for (int k = 0; k < H_ / 4; ++k) {
        ((float4*)w0)[k] = ((const float4*)(W_hh + (j          ) * H_))[k];
        ((float4*)w1)[k] = ((const float4*)(W_hh + (j + H_     ) * H_))[k];
        ((float4*)w2)[k] = ((const float4*)(W_hh + (j + 2 * H_ ) * H_))[k];
        ((float4*)w3)[k] = ((const float4*)(W_hh + (j + 3 * H_ ) * H_))[k];
    }
    const float wi0 = W_ih[j];
    const float wi1 = W_ih[j + H_];
    const float wi2 = W_ih[j + 2 * H_];
    const float wi3 = W_ih[j + 3 * H_];
    const float bs0 = b_ih[j]          + b_hh[j];
    const float bs1 = b_ih[j + H_]     + b_hh[j + H_];
    const float bs2 = b_ih[j + 2 * H_] + b_hh[j + 2 * H_];
    const float bs3 = b_ih[j + 3 * H_] + b_hh[j + 3 * H_];
    const float wout = W_out[j];
    const float bo   = b_out[0];

    float c = 0.0f, h = 0.0f;
    hbuf[grp][j] = 0.0f;                 // h0 = 0
    float xv = x[j * B_ + b];            // prefetch chunk 0 (lane j holds t=j)
    __asm__ __volatile__("" ::: "memory");

    for (int ch = 0; ch < NCH; ++ch) {
        xbuf[grp][j] = xv;               // publish current chunk
        if (ch + 1 < NCH) xv = x[((ch + 1) * CHUNK + j) * B_ + b];  // prefetch next
        __asm__ __volatile__("" ::: "memory");
        const int tbase = ch * CHUNK;
#pragma unroll 8
        for (int s = 0; s < CHUNK; ++s) {
            // Broadcast-read h_{t-1} (all 32 lanes same address: conflict-free)
            float hr[H_];
#pragma unroll
            for (int k = 0; k < H_ / 4; ++k)
                ((float4*)hr)[k] = ((const float4*)&hbuf[grp][0])[k];
            const float xk = xbuf[grp][s];
            float a0 = xk * wi0 + bs0;   // i
            float a1 = xk * wi1 + bs1;   // f
            float a2 = xk * wi2 + bs2;   // g
            float a3 = xk * wi3 + bs3;   // o
#pragma unroll
            for (int k = 0; k < H_; ++k) {
                a0 += hr[k] * w0[k];
                a1 += hr[k] * w1[k];
                a2 += hr[k] * w2[k];
                a3 += hr[k] * w3[k];
            }
            const float ig = sigmoidf_fast(a0);
            const float fg = sigmoidf_fast(a1);
            const float gg = tanhf_fast(a2);
            const float og = sigmoidf_fast(a3);
            c = fg * c + ig * gg;
            h = og * tanhf_fast(c);
            hbuf[grp][j] = h;            // publish h_t (read next step)
            __asm__ __volatile__("" ::: "memory");
            // Output projection O=1: butterfly-reduce W_out . h over the group
            float p = h * wout;
            p += __shfl_xor(p, 1, 32);
            p += __shfl_xor(p, 2, 32);
            p += __shfl_xor(p, 4, 32);
            p += __shfl_xor(p, 8, 32);
            p += __shfl_xor(p, 16, 32);
            if (j == 0) out[(tbase + s) * B_ + b] = p + bo;
        }
    }
    // Final states: hT [1,B,H] then cT [1,B,H]
    out[OUTS + b * H_ + j] = h;
    out[OUTS + B_ * H_ + b * H_ + j] = c;
}

extern "C" void kernel_launch(void* const* d_in, const int* in_sizes, int n_in,
                              void* d_out, int out_size, void* d_ws, size_t ws_size,
                              hipStream_t stream) {
    const float* x     = (const float*)d_in[0];
    const float* W_ih  = (const float*)d_in[1];
    const float* W_hh  = (const float*)d_in[2];
    const float* b_ih  = (const float*)d_in[3];
    const float* b_hh  = (const float*)d_in[4];
    const float* W_out = (const float*)d_in[5];
    const float* b_out = (const float*)d_in[6];
    lstm_fused<<<dim3(B_ / GPB), dim3(GPB * 32), 0, stream>>>(
        x, W_ih, W_hh, b_ih, b_hh, W_out, b_out, (float*)d_out);
}

// Round 2
// 1097.268 us; speedup vs baseline: 1.1349x; 1.1349x over previous
//
#include <hip/hip_runtime.h>

// LSTM T=2048,B=2048,H=32,I=1,O=1 fused in ONE kernel.
// R2 decomposition: ONE wave64 per batch element. Lane l: j = l&31 (hidden
// unit), half = l>>5. half0 computes gates i,f of unit j; half1 computes g,o.
// Cross-half exchange of (g,o) via __shfl_xor(.,32). h broadcast via LDS,
// wave-synchronous (no barriers). 2048 waves = 2 waves/SIMD so dependency
// stalls of one wave are filled by the other's issue.
// Weights: 64 floats/thread, pinned in VGPRs via opaque asm identity to
// defeat the rematerialization seen in R1 (VGPR_Count=88 < working set).

namespace {
constexpr int T_ = 2048;
constexpr int B_ = 2048;
constexpr int H_ = 32;
constexpr int WPB = 4;              // waves (= batch elements) per block
constexpr int CHUNK = 64;           // timesteps of x staged per LDS chunk
constexpr int NCH = T_ / CHUNK;     // 32
constexpr int OUTS = T_ * B_;       // floats of outs [T,B,1]

typedef float v4f __attribute__((ext_vector_type(4)));

__device__ __forceinline__ float rcp_(float v) { return __builtin_amdgcn_rcpf(v); }
__device__ __forceinline__ float ex2_(float v) { return __builtin_amdgcn_exp2f(v); }
} // namespace

__global__ __launch_bounds__(256, 2) void lstm_fused2(
    const float* __restrict__ x,      // [T,B,1]
    const float* __restrict__ W_ih,   // [4H,1]
    const float* __restrict__ W_hh,   // [4H,H]
    const float* __restrict__ b_ih,   // [4H]
    const float* __restrict__ b_hh,   // [4H]
    const float* __restrict__ W_out,  // [1,H]
    const float* __restrict__ b_out,  // [1]
    float* __restrict__ out)          // outs | hT | cT
{
    const int l    = threadIdx.x & 63;  // lane in wave
    const int wv   = threadIdx.x >> 6;  // wave (batch elem) within block
    const int j    = l & 31;            // hidden unit
    const int half = l >> 5;            // 0: gates i,f   1: gates g,o
    const int b    = blockIdx.x * WPB + wv;

    __shared__ float hbuf[WPB][H_];
    __shared__ float xbuf[WPB][CHUNK];

    const int gA = half * 2;      // i or g
    const int gB = half * 2 + 1;  // f or o

    // Recurrent weight rows for the two gates this lane owns (64 VGPRs).
    v4f wA[H_ / 4], wB[H_ / 4];
#pragma unroll
    for (int k = 0; k < H_ / 4; ++k) {
        wA[k] = ((const v4f*)(W_hh + (gA * H_ + j) * H_))[k];
        wB[k] = ((const v4f*)(W_hh + (gB * H_ + j) * H_))[k];
    }
    // Pin in VGPRs: opaque to the optimizer -> no remat, no re-load per step.
#pragma unroll
    for (int k = 0; k < H_ / 4; ++k) {
        __asm__ __volatile__("" : "+v"(wA[k]));
        __asm__ __volatile__("" : "+v"(wB[k]));
    }

    const float wiA = W_ih[gA * H_ + j];
    const float wiB = W_ih[gB * H_ + j];
    const float bsA = b_ih[gA * H_ + j] + b_hh[gA * H_ + j];
    const float bsB = b_ih[gB * H_ + j] + b_hh[gB * H_ + j];
    // Unified activation for gate A: half0 sigmoid(i), half1 tanh(g):
    //   r = rcp(1 + exp2(sclA * a));  act = cA0 + cA1 * r
    const float sclA = half ? 2.885390081777927f : -1.442695040888963f;
    const float cA0  = half ? 1.0f : 0.0f;
    const float cA1  = half ? -2.0f : 1.0f;
    const float wout = W_out[j];
    const float bo   = b_out[0];

    float c = 0.0f, h = 0.0f;
    if (half == 0) hbuf[wv][j] = 0.0f;   // h0 = 0
    float xv = x[l * B_ + b];            // prefetch chunk 0 (lane l holds t=l)
    __asm__ __volatile__("" ::: "memory");

    for (int ch = 0; ch < NCH; ++ch) {
        xbuf[wv][l] = xv;                                        // publish chunk
        if (ch + 1 < NCH) xv = x[((ch + 1) * CHUNK + l) * B_ + b]; // prefetch
        __asm__ __volatile__("" ::: "memory");
        const int tbase = ch * CHUNK;
#pragma unroll 4
        for (int s = 0; s < CHUNK; ++s) {
            // Broadcast-read h_{t-1} (all lanes same address: conflict-free)
            float hr[H_];
#pragma unroll
            for (int k = 0; k < H_ / 4; ++k)
                ((v4f*)hr)[k] = ((const v4f*)&hbuf[wv][0])[k];
            const float xk = xbuf[wv][s];
            float aA = xk * wiA + bsA;
            float aB = xk * wiB + bsB;
#pragma unroll
            for (int k = 0; k < H_ / 4; ++k) {
                aA += hr[4 * k + 0] * wA[k].x;
                aA += hr[4 * k + 1] * wA[k].y;
                aA += hr[4 * k + 2] * wA[k].z;
                aA += hr[4 * k + 3] * wA[k].w;
                aB += hr[4 * k + 0] * wB[k].x;
                aB += hr[4 * k + 1] * wB[k].y;
                aB += hr[4 * k + 2] * wB[k].z;
                aB += hr[4 * k + 3] * wB[k].w;
            }
            const float actA = cA0 + cA1 * rcp_(1.0f + ex2_(sclA * aA));
            const float actB = rcp_(1.0f + ex2_(-1.442695040888963f * aB));
            // half0 receives (g,o) from half1 (half1 gets garbage, unused)
            const float g_in = __shfl_xor(actA, 32, 64);
            const float o_in = __shfl_xor(actB, 32, 64);
            c = actB * c + actA * g_in;   // half0: f*c + i*g
            const float tc = 1.0f - 2.0f * rcp_(1.0f + ex2_(2.885390081777927f * c));
            h = o_in * tc;
            if (half == 0) hbuf[wv][j] = h;   // publish h_t ASAP (critical path)
            __asm__ __volatile__("" ::: "memory");
            // Output projection O=1: reduce over half0's 32 lanes
            float p = h * wout;
            p += __shfl_xor(p, 1, 64);
            p += __shfl_xor(p, 2, 64);
            p += __shfl_xor(p, 4, 64);
            p += __shfl_xor(p, 8, 64);
            p += __shfl_xor(p, 16, 64);
            if (l == 0) out[(tbase + s) * B_ + b] = p + bo;
        }
    }
    // Final states: hT [1,B,H] then cT [1,B,H] (valid h,c live on half0)
    if (half == 0) {
        out[OUTS + b * H_ + j] = h;
        out[OUTS + B_ * H_ + b * H_ + j] = c;
    }
}

extern "C" void kernel_launch(void* const* d_in, const int* in_sizes, int n_in,
                              void* d_out, int out_size, void* d_ws, size_t ws_size,
                              hipStream_t stream) {
    const float* x     = (const float*)d_in[0];
    const float* W_ih  = (const float*)d_in[1];
    const float* W_hh  = (const float*)d_in[2];
    const float* b_ih  = (const float*)d_in[3];
    const float* b_hh  = (const float*)d_in[4];
    const float* W_out = (const float*)d_in[5];
    const float* b_out = (const float*)d_in[6];
    lstm_fused2<<<dim3(B_ / WPB), dim3(WPB * 64), 0, stream>>>(
        x, W_ih, W_hh, b_ih, b_hh, W_out, b_out, (float*)d_out);
}

// Round 3
// 989.115 us; speedup vs baseline: 1.2590x; 1.1093x over previous
//
#include <hip/hip_runtime.h>

// LSTM T=2048,B=2048,H=32,I=1,O=1 fused in ONE kernel.
// R3: one wave64 per TWO batch elements (one per 32-lane half). Lane l owns
// hidden unit j=l&31 of element p=l>>5 and computes ALL FOUR gates:
// no cross-half shfl on the recurrent critical path (R2's ds_bpermute was
// ~100+ cyc of the step chain). Gate dot products are k-pairwise float2
// accumulators -> v_pk_fma_f32, 4 independent 16-deep chains. Activation
// exp2 scale factors are pre-baked into weights/biases. Weights pinned in
// VGPRs via opaque asm (VGPR_Count=68 in R2 proved this works).
// 1024 waves = 1 wave/SIMD, 256 blocks x 256 threads on 256 CUs.

namespace {
constexpr int T_ = 2048;
constexpr int B_ = 2048;
constexpr int H_ = 32;
constexpr int WPB = 4;              // waves per block; each wave = 2 elements
constexpr int EPB = WPB * 2;        // batch elements per block
constexpr int CHUNK = 32;           // timesteps of x staged per LDS chunk
constexpr int NCH = T_ / CHUNK;     // 64
constexpr int OUTS = T_ * B_;       // floats of outs [T,B,1]
constexpr float L2E = 1.442695040888963f;  // log2(e)

typedef float v2f __attribute__((ext_vector_type(2)));
typedef float v4f __attribute__((ext_vector_type(4)));

__device__ __forceinline__ float rcp_(float v){ return __builtin_amdgcn_rcpf(v); }
__device__ __forceinline__ float ex2_(float v){ return __builtin_amdgcn_exp2f(v); }
} // namespace

__global__ __launch_bounds__(256, 1) void lstm_fused3(
    const float* __restrict__ x,      // [T,B,1]
    const float* __restrict__ W_ih,   // [4H,1]
    const float* __restrict__ W_hh,   // [4H,H]
    const float* __restrict__ b_ih,   // [4H]
    const float* __restrict__ b_hh,   // [4H]
    const float* __restrict__ W_out,  // [1,H]
    const float* __restrict__ b_out,  // [1]
    float* __restrict__ out)          // outs | hT | cT
{
    const int l  = threadIdx.x & 63;
    const int wv = threadIdx.x >> 6;
    const int j  = l & 31;            // hidden unit
    const int p  = l >> 5;            // element half within wave
    const int e  = blockIdx.x * EPB + wv * 2 + p;

    __shared__ __align__(16) float hbuf[WPB][2][H_];
    __shared__ float xbuf[WPB][2][CHUNK];

    // Activation domain pre-scales: sigmoid uses exp2(-L2E*a), tanh uses
    // exp2(2*L2E*a). Bake into weights so no dependent mul before exp2.
    const float sI = -L2E, sF = -L2E, sG = 2.0f * L2E, sO = -L2E;

    // W_hh rows j (i), j+H (f), j+2H (g), j+3H (o); packed over k-pairs.
    v2f wi[H_/2], wf[H_/2], wg[H_/2], wo[H_/2];
#pragma unroll
    for (int k2 = 0; k2 < H_/2; ++k2) {
        const float* ri = W_hh + (0*H_ + j) * H_;
        const float* rf = W_hh + (1*H_ + j) * H_;
        const float* rg = W_hh + (2*H_ + j) * H_;
        const float* ro = W_hh + (3*H_ + j) * H_;
        wi[k2] = (v2f){ ri[2*k2] * sI, ri[2*k2+1] * sI };
        wf[k2] = (v2f){ rf[2*k2] * sF, rf[2*k2+1] * sF };
        wg[k2] = (v2f){ rg[2*k2] * sG, rg[2*k2+1] * sG };
        wo[k2] = (v2f){ ro[2*k2] * sO, ro[2*k2+1] * sO };
    }
    // Pin in VGPRs: values become opaque -> not rematerializable as reloads.
#pragma unroll
    for (int k2 = 0; k2 < H_/2; ++k2) {
        __asm__ __volatile__("" : "+v"(wi[k2]));
        __asm__ __volatile__("" : "+v"(wf[k2]));
        __asm__ __volatile__("" : "+v"(wg[k2]));
        __asm__ __volatile__("" : "+v"(wo[k2]));
    }

    const float wxi = W_ih[0*H_+j] * sI, wxf = W_ih[1*H_+j] * sF;
    const float wxg = W_ih[2*H_+j] * sG, wxo = W_ih[3*H_+j] * sO;
    const float bi  = (b_ih[0*H_+j] + b_hh[0*H_+j]) * sI;
    const float bf  = (b_ih[1*H_+j] + b_hh[1*H_+j]) * sF;
    const float bg  = (b_ih[2*H_+j] + b_hh[2*H_+j]) * sG;
    const float bo_ = (b_ih[3*H_+j] + b_hh[3*H_+j]) * sO;
    const float wout = W_out[j];
    const float bout = b_out[0];

    float c = 0.0f, h = 0.0f;
    hbuf[wv][p][j] = 0.0f;               // h0 = 0 (all 64 lanes distinct slots)
    float xv = x[j * B_ + e];            // prefetch chunk 0 (lane covers t=j)
    __asm__ __volatile__("" ::: "memory");

    for (int ch = 0; ch < NCH; ++ch) {
        xbuf[wv][p][j] = xv;                                       // publish
        if (ch + 1 < NCH) xv = x[((ch + 1) * CHUNK + j) * B_ + e]; // prefetch
        __asm__ __volatile__("" ::: "memory");
        const int tbase = ch * CHUNK;
#pragma unroll 4
        for (int s = 0; s < CHUNK; ++s) {
            // Broadcast-read own element's h_{t-1} (per half: same address
            // on 32 lanes -> broadcast; 2 addresses per wave -> free).
            v4f hq[H_/4];
#pragma unroll
            for (int q = 0; q < H_/4; ++q)
                hq[q] = ((const v4f*)&hbuf[wv][p][0])[q];
            const float xk = xbuf[wv][p][s];
            // x-term + bias: independent of hr -> off the dot chain.
            const float xi = bi  + xk * wxi;
            const float xf = bf  + xk * wxf;
            const float xg = bg  + xk * wxg;
            const float xo = bo_ + xk * wxo;
            // 4 independent 16-deep packed-FMA chains (pairwise over k).
            v2f ai = {0.f, 0.f}, af = {0.f, 0.f}, ag = {0.f, 0.f}, ao = {0.f, 0.f};
#pragma unroll
            for (int q = 0; q < H_/4; ++q) {
                const v2f hlo = (v2f){ hq[q].x, hq[q].y };
                const v2f hhi = (v2f){ hq[q].z, hq[q].w };
                ai += wi[2*q] * hlo;  ai += wi[2*q+1] * hhi;
                af += wf[2*q] * hlo;  af += wf[2*q+1] * hhi;
                ag += wg[2*q] * hlo;  ag += wg[2*q+1] * hhi;
                ao += wo[2*q] * hlo;  ao += wo[2*q+1] * hhi;
            }
            const float iv = rcp_(1.0f + ex2_(ai.x + ai.y + xi));
            const float fv = rcp_(1.0f + ex2_(af.x + af.y + xf));
            const float gv = 1.0f - 2.0f * rcp_(1.0f + ex2_(ag.x + ag.y + xg));
            const float ov = rcp_(1.0f + ex2_(ao.x + ao.y + xo));
            c = fv * c + iv * gv;
            const float tc = 1.0f - 2.0f * rcp_(1.0f + ex2_(2.0f * L2E * c));
            h = ov * tc;
            hbuf[wv][p][j] = h;          // publish h_t immediately
            __asm__ __volatile__("" ::: "memory");
            // Output projection (off the recurrent chain): reduce within half.
            float pr = h * wout;
            pr += __shfl_xor(pr, 1, 32);
            pr += __shfl_xor(pr, 2, 32);
            pr += __shfl_xor(pr, 4, 32);
            pr += __shfl_xor(pr, 8, 32);
            pr += __shfl_xor(pr, 16, 32);
            if (j == 0) out[(tbase + s) * B_ + e] = pr + bout;
        }
    }
    // Final states: hT [1,B,H] then cT [1,B,H] — valid on every lane.
    out[OUTS + e * H_ + j] = h;
    out[OUTS + B_ * H_ + e * H_ + j] = c;
}

extern "C" void kernel_launch(void* const* d_in, const int* in_sizes, int n_in,
                              void* d_out, int out_size, void* d_ws, size_t ws_size,
                              hipStream_t stream) {
    const float* x     = (const float*)d_in[0];
    const float* W_ih  = (const float*)d_in[1];
    const float* W_hh  = (const float*)d_in[2];
    const float* b_ih  = (const float*)d_in[3];
    const float* b_hh  = (const float*)d_in[4];
    const float* W_out = (const float*)d_in[5];
    const float* b_out = (const float*)d_in[6];
    lstm_fused3<<<dim3(B_ / EPB), dim3(256), 0, stream>>>(
        x, W_ih, W_hh, b_ih, b_hh, W_out, b_out, (float*)d_out);
}

// Round 4
// 735.968 us; speedup vs baseline: 1.6921x; 1.3440x over previous
//
#include <hip/hip_runtime.h>

// LSTM T=2048,B=2048,H=32,I=1,O=1 fused in ONE kernel.
// R4: R3 decomposition (wave64 = 2 batch elements, lane owns unit j of its
// half's element, computes all 4 gates). Changes vs R3, all aimed at the
// per-step WAIT chain (wall = single-wave critical path; R2 proved extra
// waves/SIMD don't shorten a serial chain):
//  - output projection via DPP (row_shr 1/2/4/8 + row_bcast:15): pure VALU,
//    replaces 5 dependent ds_swizzle+waitcnt round trips (~250-300 cyc/step)
//  - x broadcast via v_readlane from a register chunk: xbuf LDS removed
//  - step reordered: publish h -> issue next-step ds_read_b128 x8 -> DPP
//    reduce + store overlap the LDS read latency
//  - dot: 2 accumulators/gate (8-deep v_pk_fma chains)

namespace {
constexpr int T_ = 2048;
constexpr int B_ = 2048;
constexpr int H_ = 32;
constexpr int WPB = 4;              // waves per block; each wave = 2 elements
constexpr int EPB = WPB * 2;        // batch elements per block
constexpr int CHUNK = 32;           // timesteps of x held in one VGPR
constexpr int NCH = T_ / CHUNK;     // 64
constexpr int OUTS = T_ * B_;       // floats of outs [T,B,1]
constexpr float L2E = 1.442695040888963f;  // log2(e)

typedef float v2f __attribute__((ext_vector_type(2)));
typedef float v4f __attribute__((ext_vector_type(4)));

__device__ __forceinline__ float rcp_(float v){ return __builtin_amdgcn_rcpf(v); }
__device__ __forceinline__ float ex2_(float v){ return __builtin_amdgcn_exp2f(v); }

template <int CTRL, int RM, int BM, bool BC>
__device__ __forceinline__ float dpp_add(float acc, float src) {
    // acc + dpp_move(src); old=0 so masked/out-of-range lanes contribute 0
    int mv = __builtin_amdgcn_update_dpp(0, __builtin_bit_cast(int, src),
                                         CTRL, RM, BM, BC);
    return acc + __builtin_bit_cast(float, mv);
}

// Sum within each 32-lane half; result in lane 31 (half0) / lane 63 (half1).
__device__ __forceinline__ float half_sum32(float v) {
    v = dpp_add<0x111, 0xF, 0xF, true >(v, v);  // row_shr:1
    v = dpp_add<0x112, 0xF, 0xF, true >(v, v);  // row_shr:2
    v = dpp_add<0x114, 0xF, 0xF, true >(v, v);  // row_shr:4
    v = dpp_add<0x118, 0xF, 0xF, true >(v, v);  // row_shr:8  -> lane15/31/47/63 = row sums
    v = dpp_add<0x142, 0xA, 0xF, false>(v, v);  // row_bcast:15 into rows 1,3
    return v;
}
} // namespace

__global__ __launch_bounds__(256, 1) void lstm_fused4(
    const float* __restrict__ x,      // [T,B,1]
    const float* __restrict__ W_ih,   // [4H,1]
    const float* __restrict__ W_hh,   // [4H,H]
    const float* __restrict__ b_ih,   // [4H]
    const float* __restrict__ b_hh,   // [4H]
    const float* __restrict__ W_out,  // [1,H]
    const float* __restrict__ b_out,  // [1]
    float* __restrict__ out)          // outs | hT | cT
{
    const int l  = threadIdx.x & 63;
    const int wv = threadIdx.x >> 6;
    const int j  = l & 31;            // hidden unit
    const int p  = l >> 5;            // element half within wave
    const int e  = blockIdx.x * EPB + wv * 2 + p;

    __shared__ __align__(16) float hbuf[WPB][2][H_];

    const float sI = -L2E, sF = -L2E, sG = 2.0f * L2E, sO = -L2E;

    // W_hh rows j (i), j+H (f), j+2H (g), j+3H (o); packed k-pairs, pre-scaled.
    v2f wi[H_/2], wf[H_/2], wg[H_/2], wo[H_/2];
#pragma unroll
    for (int k2 = 0; k2 < H_/2; ++k2) {
        const float* ri = W_hh + (0*H_ + j) * H_;
        const float* rf = W_hh + (1*H_ + j) * H_;
        const float* rg = W_hh + (2*H_ + j) * H_;
        const float* ro = W_hh + (3*H_ + j) * H_;
        wi[k2] = (v2f){ ri[2*k2] * sI, ri[2*k2+1] * sI };
        wf[k2] = (v2f){ rf[2*k2] * sF, rf[2*k2+1] * sF };
        wg[k2] = (v2f){ rg[2*k2] * sG, rg[2*k2+1] * sG };
        wo[k2] = (v2f){ ro[2*k2] * sO, ro[2*k2+1] * sO };
    }
#pragma unroll
    for (int k2 = 0; k2 < H_/2; ++k2) {       // pin in VGPRs (no remat)
        __asm__ __volatile__("" : "+v"(wi[k2]));
        __asm__ __volatile__("" : "+v"(wf[k2]));
        __asm__ __volatile__("" : "+v"(wg[k2]));
        __asm__ __volatile__("" : "+v"(wo[k2]));
    }

    const float wxi = W_ih[0*H_+j] * sI, wxf = W_ih[1*H_+j] * sF;
    const float wxg = W_ih[2*H_+j] * sG, wxo = W_ih[3*H_+j] * sO;
    const float bi  = (b_ih[0*H_+j] + b_hh[0*H_+j]) * sI;
    const float bf  = (b_ih[1*H_+j] + b_hh[1*H_+j]) * sF;
    const float bg  = (b_ih[2*H_+j] + b_hh[2*H_+j]) * sG;
    const float bo_ = (b_ih[3*H_+j] + b_hh[3*H_+j]) * sO;
    const float wout = W_out[j];
    const float bout = b_out[0];

    float c = 0.0f, h = 0.0f;
    hbuf[wv][p][j] = 0.0f;               // h0 = 0
    __asm__ __volatile__("" ::: "memory");
    v4f hq[H_/4];
#pragma unroll
    for (int q = 0; q < H_/4; ++q)       // h_0 fragments for step 0
        hq[q] = ((const v4f*)&hbuf[wv][p][0])[q];

    float xcur = x[j * B_ + e];          // chunk 0: lane j holds t=j

    for (int ch = 0; ch < NCH; ++ch) {
        float xnext = 0.0f;
        if (ch + 1 < NCH) xnext = x[((ch + 1) * CHUNK + j) * B_ + e];
        const int tbase = ch * CHUNK;
#pragma unroll 4
        for (int s = 0; s < CHUNK; ++s) {
            // x-term: register broadcast via readlane (no DS, h-independent,
            // schedulable under the in-flight hq reads)
            const int xr0 = __builtin_amdgcn_readlane(__builtin_bit_cast(int, xcur), s);
            const int xr1 = __builtin_amdgcn_readlane(__builtin_bit_cast(int, xcur), s + 32);
            const float xk = p ? __builtin_bit_cast(float, xr1)
                               : __builtin_bit_cast(float, xr0);
            const float xi = bi  + xk * wxi;
            const float xf = bf  + xk * wxf;
            const float xg = bg  + xk * wxg;
            const float xo = bo_ + xk * wxo;
            // dot: 2 accumulators per gate, 8-deep packed-FMA chains
            v2f ai0 = {0,0}, ai1 = {0,0}, af0 = {0,0}, af1 = {0,0};
            v2f ag0 = {0,0}, ag1 = {0,0}, ao0 = {0,0}, ao1 = {0,0};
#pragma unroll
            for (int q = 0; q < H_/4; ++q) {
                const v2f hlo = (v2f){ hq[q].x, hq[q].y };
                const v2f hhi = (v2f){ hq[q].z, hq[q].w };
                ai0 += wi[2*q] * hlo;  ai1 += wi[2*q+1] * hhi;
                af0 += wf[2*q] * hlo;  af1 += wf[2*q+1] * hhi;
                ag0 += wg[2*q] * hlo;  ag1 += wg[2*q+1] * hhi;
                ao0 += wo[2*q] * hlo;  ao1 += wo[2*q+1] * hhi;
            }
            const v2f ai = ai0 + ai1, af = af0 + af1;
            const v2f ag = ag0 + ag1, ao = ao0 + ao1;
            const float iv = rcp_(1.0f + ex2_(ai.x + ai.y + xi));
            const float fv = rcp_(1.0f + ex2_(af.x + af.y + xf));
            const float gv = 1.0f - 2.0f * rcp_(1.0f + ex2_(ag.x + ag.y + xg));
            const float ov = rcp_(1.0f + ex2_(ao.x + ao.y + xo));
            c = fv * c + iv * gv;
            const float tc = 1.0f - 2.0f * rcp_(1.0f + ex2_((2.0f * L2E) * c));
            h = ov * tc;
            hbuf[wv][p][j] = h;           // publish h_t
            __asm__ __volatile__("" ::: "memory");
            // issue NEXT step's h reads immediately; reduce below hides latency
#pragma unroll
            for (int q = 0; q < H_/4; ++q)
                hq[q] = ((const v4f*)&hbuf[wv][p][0])[q];
            // output projection: DPP half-sum (pure VALU, no lgkm waits)
            const float pr = half_sum32(h * wout);
            if ((l & 31) == 31) out[(tbase + s) * B_ + e] = pr + bout;
        }
        xcur = xnext;
    }
    // Final states: hT [1,B,H] then cT [1,B,H] — valid on every lane.
    out[OUTS + e * H_ + j] = h;
    out[OUTS + B_ * H_ + e * H_ + j] = c;
}

extern "C" void kernel_launch(void* const* d_in, const int* in_sizes, int n_in,
                              void* d_out, int out_size, void* d_ws, size_t ws_size,
                              hipStream_t stream) {
    const float* x     = (const float*)d_in[0];
    const float* W_ih  = (const float*)d_in[1];
    const float* W_hh  = (const float*)d_in[2];
    const float* b_ih  = (const float*)d_in[3];
    const float* b_hh  = (const float*)d_in[4];
    const float* W_out = (const float*)d_in[5];
    const float* b_out = (const float*)d_in[6];
    lstm_fused4<<<dim3(B_ / EPB), dim3(256), 0, stream>>>(
        x, W_ih, W_hh, b_ih, b_hh, W_out, b_out, (float*)d_out);
}

// Round 7
// 723.551 us; speedup vs baseline: 1.7211x; 1.0172x over previous
//
#include <hip/hip_runtime.h>

// LSTM T=2048,B=2048,H=32,I=1,O=1 fused in ONE kernel.
// R7: R4 structure (wave64 = 2 batch elements in lockstep halves -> one
// instruction stream serves 2 elements; lane owns unit j of its half's
// element, computes all 4 gates; f32 throughout -> absmax ~1e-3).
// Changes vs R4, targeting the ~90 excess VALU instrs/step diagnosed from
// VALUBusy (64.6% x 860cyc = 277 instrs vs ~130 in source = AGPR copies):
//  - amdgpu_waves_per_eu(1,1): commit allocator to full register budget
//  - weight pins (zero-instr asm "+v") moved INSIDE the step loop: values
//    must be VGPR-class every iteration -> no AGPR parking
//  - dot accumulators initialized with the x-terms (saves 4 adds/step)
//  - running output offset (1 add/step)
// Kept: DPP O=1 reduction (no lgkm waits), v_readlane x-broadcast,
// publish-h -> issue-reads -> reduce/store overlap.

namespace {
constexpr int T_ = 2048;
constexpr int B_ = 2048;
constexpr int H_ = 32;
constexpr int WPB = 4;              // waves per block; each wave = 2 elements
constexpr int EPB = WPB * 2;        // batch elements per block
constexpr int CHUNK = 32;           // timesteps of x held in one VGPR
constexpr int NCH = T_ / CHUNK;     // 64
constexpr int OUTS = T_ * B_;       // floats of outs [T,B,1]
constexpr float L2E = 1.442695040888963f;  // log2(e)

typedef float v2f __attribute__((ext_vector_type(2)));
typedef float v4f __attribute__((ext_vector_type(4)));

__device__ __forceinline__ float rcp_(float v){ return __builtin_amdgcn_rcpf(v); }
__device__ __forceinline__ float ex2_(float v){ return __builtin_amdgcn_exp2f(v); }

template <int CTRL, int RM, int BM, bool BC>
__device__ __forceinline__ float dpp_add(float acc, float src) {
    int mv = __builtin_amdgcn_update_dpp(0, __builtin_bit_cast(int, src),
                                         CTRL, RM, BM, BC);
    return acc + __builtin_bit_cast(float, mv);
}
// Sum within each 32-lane half; result in lane 31 (half0) / lane 63 (half1).
__device__ __forceinline__ float half_sum32(float v) {
    v = dpp_add<0x111, 0xF, 0xF, true >(v, v);  // row_shr:1
    v = dpp_add<0x112, 0xF, 0xF, true >(v, v);  // row_shr:2
    v = dpp_add<0x114, 0xF, 0xF, true >(v, v);  // row_shr:4
    v = dpp_add<0x118, 0xF, 0xF, true >(v, v);  // row_shr:8
    v = dpp_add<0x142, 0xA, 0xF, false>(v, v);  // row_bcast:15 -> rows 1,3
    return v;
}
} // namespace

__global__ __launch_bounds__(256, 1)
__attribute__((amdgpu_waves_per_eu(1, 1)))
void lstm_fused7(
    const float* __restrict__ x,      // [T,B,1]
    const float* __restrict__ W_ih,   // [4H,1]
    const float* __restrict__ W_hh,   // [4H,H]
    const float* __restrict__ b_ih,   // [4H]
    const float* __restrict__ b_hh,   // [4H]
    const float* __restrict__ W_out,  // [1,H]
    const float* __restrict__ b_out,  // [1]
    float* __restrict__ out)          // outs | hT | cT
{
    const int l  = threadIdx.x & 63;
    const int wv = threadIdx.x >> 6;
    const int j  = l & 31;            // hidden unit
    const int p  = l >> 5;            // element half within wave
    const int e  = blockIdx.x * EPB + wv * 2 + p;

    __shared__ __align__(16) float hbuf[WPB][2][H_];

    const float sI = -L2E, sF = -L2E, sG = 2.0f * L2E, sO = -L2E;

    // W_hh rows j (i), j+H (f), j+2H (g), j+3H (o); packed k-pairs, pre-scaled
    // so activations need no dependent mul before exp2.
    v2f wi[H_/2], wf[H_/2], wg[H_/2], wo[H_/2];
#pragma unroll
    for (int k2 = 0; k2 < H_/2; ++k2) {
        const float* ri = W_hh + (0*H_ + j) * H_;
        const float* rf = W_hh + (1*H_ + j) * H_;
        const float* rg = W_hh + (2*H_ + j) * H_;
        const float* ro = W_hh + (3*H_ + j) * H_;
        wi[k2] = (v2f){ ri[2*k2] * sI, ri[2*k2+1] * sI };
        wf[k2] = (v2f){ rf[2*k2] * sF, rf[2*k2+1] * sF };
        wg[k2] = (v2f){ rg[2*k2] * sG, rg[2*k2+1] * sG };
        wo[k2] = (v2f){ ro[2*k2] * sO, ro[2*k2+1] * sO };
    }

    const float wxi = W_ih[0*H_+j] * sI, wxf = W_ih[1*H_+j] * sF;
    const float wxg = W_ih[2*H_+j] * sG, wxo = W_ih[3*H_+j] * sO;
    const float bi  = (b_ih[0*H_+j] + b_hh[0*H_+j]) * sI;
    const float bf  = (b_ih[1*H_+j] + b_hh[1*H_+j]) * sF;
    const float bg  = (b_ih[2*H_+j] + b_hh[2*H_+j]) * sG;
    const float bo_ = (b_ih[3*H_+j] + b_hh[3*H_+j]) * sO;
    const float wout = W_out[j];
    const float bout = b_out[0];

    float c = 0.0f, h = 0.0f;
    hbuf[wv][p][j] = 0.0f;               // h0 = 0
    __asm__ __volatile__("" ::: "memory");
    v4f hq[H_/4];
#pragma unroll
    for (int q = 0; q < H_/4; ++q)       // h_0 fragments for step 0
        hq[q] = ((const v4f*)&hbuf[wv][p][0])[q];

    float xcur = x[j * B_ + e];          // chunk 0: lane j holds t=j
    int outOff = e;                      // running offset: out[t*B_+e]

    for (int ch = 0; ch < NCH; ++ch) {
        float xnext = 0.0f;
        if (ch + 1 < NCH) xnext = x[((ch + 1) * CHUNK + j) * B_ + e];
#pragma unroll 8
        for (int s = 0; s < CHUNK; ++s) {
            // In-loop zero-instruction pins: weights must be VGPR-class here
            // every iteration -> allocator cannot park them in AGPRs.
#pragma unroll
            for (int k2 = 0; k2 < H_/2; ++k2) {
                __asm__ __volatile__("" : "+v"(wi[k2]));
                __asm__ __volatile__("" : "+v"(wf[k2]));
                __asm__ __volatile__("" : "+v"(wg[k2]));
                __asm__ __volatile__("" : "+v"(wo[k2]));
            }
            // x broadcast: register readlane (h-independent, off the chain)
            const int xr0 = __builtin_amdgcn_readlane(__builtin_bit_cast(int, xcur), s);
            const int xr1 = __builtin_amdgcn_readlane(__builtin_bit_cast(int, xcur), s + 32);
            const float xk = p ? __builtin_bit_cast(float, xr1)
                               : __builtin_bit_cast(float, xr0);
            // dot accumulators start at the x-term (saves the merge adds)
            v2f ai0 = {bi  + xk * wxi, 0.f}, ai1 = {0.f, 0.f};
            v2f af0 = {bf  + xk * wxf, 0.f}, af1 = {0.f, 0.f};
            v2f ag0 = {bg  + xk * wxg, 0.f}, ag1 = {0.f, 0.f};
            v2f ao0 = {bo_ + xk * wxo, 0.f}, ao1 = {0.f, 0.f};
#pragma unroll
            for (int q = 0; q < H_/4; ++q) {
                const v2f hlo = (v2f){ hq[q].x, hq[q].y };
                const v2f hhi = (v2f){ hq[q].z, hq[q].w };
                ai0 += wi[2*q] * hlo;  ai1 += wi[2*q+1] * hhi;
                af0 += wf[2*q] * hlo;  af1 += wf[2*q+1] * hhi;
                ag0 += wg[2*q] * hlo;  ag1 += wg[2*q+1] * hhi;
                ao0 += wo[2*q] * hlo;  ao1 += wo[2*q+1] * hhi;
            }
            const v2f ai = ai0 + ai1, af = af0 + af1;
            const v2f ag = ag0 + ag1, ao = ao0 + ao1;
            const float iv = rcp_(1.0f + ex2_(ai.x + ai.y));
            const float fv = rcp_(1.0f + ex2_(af.x + af.y));
            const float gv = 1.0f - 2.0f * rcp_(1.0f + ex2_(ag.x + ag.y));
            const float ov = rcp_(1.0f + ex2_(ao.x + ao.y));
            c = fv * c + iv * gv;
            const float tc = 1.0f - 2.0f * rcp_(1.0f + ex2_((2.0f * L2E) * c));
            h = ov * tc;
            hbuf[wv][p][j] = h;           // publish h_t
            __asm__ __volatile__("" ::: "memory");
            // issue NEXT step's h reads immediately; work below hides latency
#pragma unroll
            for (int q = 0; q < H_/4; ++q)
                hq[q] = ((const v4f*)&hbuf[wv][p][0])[q];
            // output projection: DPP half-sum (pure VALU, no lgkm waits)
            const float pr = half_sum32(h * wout);
            if ((l & 31) == 31) out[outOff] = pr + bout;
            outOff += B_;
        }
        xcur = xnext;
    }
    // Final states: hT [1,B,H] then cT [1,B,H] — valid on every lane.
    out[OUTS + e * H_ + j] = h;
    out[OUTS + B_ * H_ + e * H_ + j] = c;
}

extern "C" void kernel_launch(void* const* d_in, const int* in_sizes, int n_in,
                              void* d_out, int out_size, void* d_ws, size_t ws_size,
                              hipStream_t stream) {
    const float* x     = (const float*)d_in[0];
    const float* W_ih  = (const float*)d_in[1];
    const float* W_hh  = (const float*)d_in[2];
    const float* b_ih  = (const float*)d_in[3];
    const float* b_hh  = (const float*)d_in[4];
    const float* W_out = (const float*)d_in[5];
    const float* b_out = (const float*)d_in[6];
    lstm_fused7<<<dim3(B_ / EPB), dim3(256), 0, stream>>>(
        x, W_ih, W_hh, b_ih, b_hh, W_out, b_out, (float*)d_out);
}